// Round 4
// baseline (1470.891 us; speedup 1.0000x reference)
//
#include <hip/hip_runtime.h>

// ---------------------------------------------------------------------------
// Fused LeNet forward, round 4.
//  - NO weights in LDS. Conv weights repacked (tiny preamble kernel) to
//    oc-minor layout in d_ws; conv inner loops index them uniformly ->
//    compiler emits s_load, weights ride the scalar pipe (SGPR FMA operand).
//  - conv1: lane=(cg 0..3, r 0..15), acc[6][4]; pool via shfl(lane+16) for
//    col boundary, shfl(lane+1) for row pair. 1800 FMA-issues/image.
//  - conv2: lane=(r 0..5, c 0..5) (36 active), acc[16] oc-inner; xv[5] loaded
//    once per (ci,kr) and reused by all 16 ocs. Pool via shfl(+1 / +6).
//  - LDS = 4 images x 1584 floats = 25.3 KB -> 6 blocks/CU (24 waves/CU).
//  - FCs block-cooperative as before (no K-split; scratch region is gone).
// ---------------------------------------------------------------------------

constexpr int THREADS = 256;
constexpr int IPB = 4;                  // images per block (1 per wave)

// per-image LDS offsets (floats)
constexpr int XS_OFF = 0;               // [3][19][20] = 1140
constexpr int P1_OFF = 0;               // [6][14][14] = 1176 (overwrites xs)
constexpr int P2_OFF = 1184;            // [400] flatten oc*25+r*5+c
constexpr int F1_OFF = 0;               // [120] (p1 dead after conv2)
constexpr int F2_OFF = 128;             // [84]
constexpr int IMG_STRIDE = 1584;
constexpr int LDS_FLOATS = IPB * IMG_STRIDE;   // 6336 floats -> 25344 B

__device__ __forceinline__ void wave_sync() {
    asm volatile("s_waitcnt lgkmcnt(0)" ::: "memory");
}

// ws[0..600)    = w1r[k=(ci*5+kr)*5+kc][8] (oc minor, 6 used, padded to 8)
// ws[600..3000) = w2r[k=(ci*5+kr)*5+kc][16] (oc minor)
__global__ void repack_weights(const float* __restrict__ w1,
                               const float* __restrict__ w2,
                               float* __restrict__ ws) {
    int t = blockIdx.x * 256 + threadIdx.x;
    if (t < 600) {
        int k = t >> 3, oc = t & 7;
        ws[t] = (oc < 6) ? w1[oc * 75 + k] : 0.f;
    } else if (t < 3000) {
        int u = t - 600;
        int k = u >> 4, oc = u & 15;
        ws[t] = w2[oc * 150 + k];
    }
}

extern "C" __global__ __launch_bounds__(THREADS, 6)
void lenet_fused(const float* __restrict__ x,
                 const float* __restrict__ wr,
                 const float* __restrict__ fc1w, const float* __restrict__ fc1b,
                 const float* __restrict__ fc2w, const float* __restrict__ fc2b,
                 const float* __restrict__ fc3w, const float* __restrict__ fc3b,
                 float* __restrict__ out)
{
    __shared__ __align__(16) float lds[LDS_FLOATS];
    const int tid  = threadIdx.x;
    const int lane = tid & 63;
    const int wv   = tid >> 6;
    const int img0 = blockIdx.x * IPB;

    float* base = lds + wv * IMG_STRIDE;

    // ---- stage input patch rows 0..18, cols 0..19 (per wave, float4) ----
    {
        const float4* xg = (const float4*)(x + (size_t)(img0 + wv) * 3072);
        float4* xs4 = (float4*)(base + XS_OFF);
        for (int i = lane; i < 285; i += 64) {       // 3ch * 19r * 5(f4)
            int c = i / 95, rem = i - c * 95;
            int r = rem / 5, c4 = rem - r * 5;
            xs4[i] = xg[c * 256 + r * 8 + c4];
        }
    }
    wave_sync();

    const float* xs = base + XS_OFF;
    float* p1 = base + P1_OFF;

    // ---- conv1 + relu + pool1 -> p1 [6][14][14] ----
    // lane = cg*16 + r ; cols 4cg..4cg+3 (cg3: 12..14 valid), rows 0..14.
    {
        const int r  = lane & 15;
        const int cg = lane >> 4;
        const int rr = (r < 15) ? r : 14;            // r==15 lanes duplicate row 14
        float acc[6][4];
        #pragma unroll
        for (int o = 0; o < 6; ++o)
            #pragma unroll
            for (int j = 0; j < 4; ++j) acc[o][j] = 0.f;

        #pragma unroll
        for (int ci = 0; ci < 3; ++ci) {
            #pragma unroll
            for (int kr = 0; kr < 5; ++kr) {
                const float* xrow = xs + ci * 380 + (rr + kr) * 20 + 4 * cg;
                float xv[8];
                #pragma unroll
                for (int j = 0; j < 8; ++j) xv[j] = xrow[j];
                const float* wk = wr + (ci * 5 + kr) * 5 * 8;   // uniform -> s_load
                #pragma unroll
                for (int kc = 0; kc < 5; ++kc) {
                    #pragma unroll
                    for (int o = 0; o < 6; ++o) {
                        const float w = wk[kc * 8 + o];
                        #pragma unroll
                        for (int j = 0; j < 4; ++j)
                            acc[o][j] = fmaf(xv[j + kc], w, acc[o][j]);
                    }
                }
            }
        }
        wave_sync();   // xs fully consumed; safe to overwrite with p1
        #pragma unroll
        for (int o = 0; o < 6; ++o) {
            float a[5];
            #pragma unroll
            for (int j = 0; j < 4; ++j) a[j] = fmaxf(acc[o][j], 0.f);
            a[4] = __shfl(a[0], lane + 16, 64);      // next cg's col0 (cg3: unused)
            float pm[4];
            #pragma unroll
            for (int j = 0; j < 4; ++j) pm[j] = fmaxf(a[j], a[j + 1]);
            float m[4];
            #pragma unroll
            for (int j = 0; j < 4; ++j)
                m[j] = fmaxf(pm[j], __shfl(pm[j], lane + 1, 64));   // row r+1
            if (r < 14) {
                float* d = p1 + o * 196 + r * 14 + 4 * cg;
                ((float2*)d)[0] = make_float2(m[0], m[1]);
                if (cg < 3) ((float2*)d)[1] = make_float2(m[2], m[3]);
            }
        }
    }
    wave_sync();

    // ---- conv2 + relu + pool2 -> p2 [16*5*5] flatten order ----
    float* p2 = base + P2_OFF;
    {
        const int l = (lane < 36) ? lane : 35;
        const int r = l / 6, c = l - r * 6;
        const float* w2r = wr + 600;
        float acc[16];
        #pragma unroll
        for (int o = 0; o < 16; ++o) acc[o] = 0.f;

        #pragma unroll
        for (int ci = 0; ci < 6; ++ci) {
            #pragma unroll
            for (int kr = 0; kr < 5; ++kr) {
                const float* prow = p1 + ci * 196 + (r + kr) * 14 + c;
                float xv[5];
                #pragma unroll
                for (int j = 0; j < 5; ++j) xv[j] = prow[j];
                const float* wk = w2r + (ci * 5 + kr) * 5 * 16;  // uniform -> s_load
                #pragma unroll
                for (int kc = 0; kc < 5; ++kc) {
                    #pragma unroll
                    for (int o = 0; o < 16; ++o)
                        acc[o] = fmaf(xv[kc], wk[kc * 16 + o], acc[o]);
                }
            }
        }
        #pragma unroll
        for (int o = 0; o < 16; ++o) {
            float a   = fmaxf(acc[o], 0.f);
            float pmv = fmaxf(a, __shfl(a, lane + 1, 64));      // col c+1
            float mv  = fmaxf(pmv, __shfl(pmv, lane + 6, 64));  // row r+1
            if (r < 5 && c < 5) p2[o * 25 + r * 5 + c] = mv;
        }
    }
    __syncthreads();   // all 4 images' p2 ready -> block-cooperative FCs

    // ---- fc1 (120x400) + relu : thread=row, one w load feeds 4 images ----
    if (tid < 120) {
        const int row = tid;
        const float4* wrow = (const float4*)(fc1w + row * 400);
        const float bz = fc1b[row];
        float acc0 = bz, acc1 = bz, acc2 = bz, acc3 = bz;
        const float4* a0p = (const float4*)(lds + 0 * IMG_STRIDE + P2_OFF);
        const float4* a1p = (const float4*)(lds + 1 * IMG_STRIDE + P2_OFF);
        const float4* a2p = (const float4*)(lds + 2 * IMG_STRIDE + P2_OFF);
        const float4* a3p = (const float4*)(lds + 3 * IMG_STRIDE + P2_OFF);
        #pragma unroll 2
        for (int k = 0; k < 100; ++k) {
            float4 w4 = wrow[k];
            float4 a0 = a0p[k], a1 = a1p[k], a2 = a2p[k], a3 = a3p[k];
            acc0 = fmaf(a0.x, w4.x, acc0); acc0 = fmaf(a0.y, w4.y, acc0);
            acc0 = fmaf(a0.z, w4.z, acc0); acc0 = fmaf(a0.w, w4.w, acc0);
            acc1 = fmaf(a1.x, w4.x, acc1); acc1 = fmaf(a1.y, w4.y, acc1);
            acc1 = fmaf(a1.z, w4.z, acc1); acc1 = fmaf(a1.w, w4.w, acc1);
            acc2 = fmaf(a2.x, w4.x, acc2); acc2 = fmaf(a2.y, w4.y, acc2);
            acc2 = fmaf(a2.z, w4.z, acc2); acc2 = fmaf(a2.w, w4.w, acc2);
            acc3 = fmaf(a3.x, w4.x, acc3); acc3 = fmaf(a3.y, w4.y, acc3);
            acc3 = fmaf(a3.z, w4.z, acc3); acc3 = fmaf(a3.w, w4.w, acc3);
        }
        lds[0 * IMG_STRIDE + F1_OFF + row] = fmaxf(acc0, 0.f);
        lds[1 * IMG_STRIDE + F1_OFF + row] = fmaxf(acc1, 0.f);
        lds[2 * IMG_STRIDE + F1_OFF + row] = fmaxf(acc2, 0.f);
        lds[3 * IMG_STRIDE + F1_OFF + row] = fmaxf(acc3, 0.f);
    }
    __syncthreads();

    // ---- fc2 (84x120) + relu ----
    if (tid < 84) {
        const int row = tid;
        const float4* wrow = (const float4*)(fc2w + row * 120);
        const float bz = fc2b[row];
        float acc0 = bz, acc1 = bz, acc2 = bz, acc3 = bz;
        const float4* f0 = (const float4*)(lds + 0 * IMG_STRIDE + F1_OFF);
        const float4* f1 = (const float4*)(lds + 1 * IMG_STRIDE + F1_OFF);
        const float4* f2 = (const float4*)(lds + 2 * IMG_STRIDE + F1_OFF);
        const float4* f3 = (const float4*)(lds + 3 * IMG_STRIDE + F1_OFF);
        #pragma unroll 2
        for (int k = 0; k < 30; ++k) {
            float4 w4 = wrow[k];
            float4 a0 = f0[k], a1 = f1[k], a2 = f2[k], a3 = f3[k];
            acc0 = fmaf(a0.x, w4.x, acc0); acc0 = fmaf(a0.y, w4.y, acc0);
            acc0 = fmaf(a0.z, w4.z, acc0); acc0 = fmaf(a0.w, w4.w, acc0);
            acc1 = fmaf(a1.x, w4.x, acc1); acc1 = fmaf(a1.y, w4.y, acc1);
            acc1 = fmaf(a1.z, w4.z, acc1); acc1 = fmaf(a1.w, w4.w, acc1);
            acc2 = fmaf(a2.x, w4.x, acc2); acc2 = fmaf(a2.y, w4.y, acc2);
            acc2 = fmaf(a2.z, w4.z, acc2); acc2 = fmaf(a2.w, w4.w, acc2);
            acc3 = fmaf(a3.x, w4.x, acc3); acc3 = fmaf(a3.y, w4.y, acc3);
            acc3 = fmaf(a3.z, w4.z, acc3); acc3 = fmaf(a3.w, w4.w, acc3);
        }
        lds[0 * IMG_STRIDE + F2_OFF + row] = fmaxf(acc0, 0.f);
        lds[1 * IMG_STRIDE + F2_OFF + row] = fmaxf(acc1, 0.f);
        lds[2 * IMG_STRIDE + F2_OFF + row] = fmaxf(acc2, 0.f);
        lds[3 * IMG_STRIDE + F2_OFF + row] = fmaxf(acc3, 0.f);
    }
    __syncthreads();

    // ---- fc3 (10x84) -> out ----
    if (tid < 40) {
        const int im  = tid / 10;
        const int row = tid - im * 10;
        const float4* wrow = (const float4*)(fc3w + row * 84);
        const float4* f2 = (const float4*)(lds + im * IMG_STRIDE + F2_OFF);
        float acc = fc3b[row];
        #pragma unroll
        for (int k = 0; k < 21; ++k) {
            float4 w4 = wrow[k];
            float4 a = f2[k];
            acc = fmaf(a.x, w4.x, acc); acc = fmaf(a.y, w4.y, acc);
            acc = fmaf(a.z, w4.z, acc); acc = fmaf(a.w, w4.w, acc);
        }
        out[(size_t)(img0 + im) * 10 + row] = acc;
    }
}

extern "C" void kernel_launch(void* const* d_in, const int* in_sizes, int n_in,
                              void* d_out, int out_size, void* d_ws, size_t ws_size,
                              hipStream_t stream) {
    const float* x    = (const float*)d_in[0];
    const float* w1   = (const float*)d_in[1];
    const float* w2   = (const float*)d_in[2];
    const float* fc1w = (const float*)d_in[3];
    const float* fc1b = (const float*)d_in[4];
    const float* fc2w = (const float*)d_in[5];
    const float* fc2b = (const float*)d_in[6];
    const float* fc3w = (const float*)d_in[7];
    const float* fc3b = (const float*)d_in[8];
    float* out = (float*)d_out;
    float* wr  = (float*)d_ws;               // 3000 floats = 12 KB

    repack_weights<<<12, 256, 0, stream>>>(w1, w2, wr);

    const int B = in_sizes[0] / 3072;        // 8192
    const int grid = B / IPB;                // 2048
    lenet_fused<<<grid, THREADS, 0, stream>>>(x, wr, fc1w, fc1b,
                                              fc2w, fc2b, fc3w, fc3b, out);
}

// Round 5
// 1057.061 us; speedup vs baseline: 1.3915x; 1.3915x over previous
//
#include <hip/hip_runtime.h>

// ---------------------------------------------------------------------------
// Fused LeNet forward, round 5 (= round 4 structure, fixed launch bounds).
//  - ROUND-4 BUG: __launch_bounds__(256,6) capped VGPRs at 40 -> massive
//    scratch spill (FETCH 2.7 GB, 1.4 ms). (256,3) caps at ~80-85: kernel
//    fits (no spill) and HW still gives 6 waves/SIMD at <=85 VGPR, matching
//    the 25.3 KB LDS limit of 6 blocks/CU.
//  - Conv weights repacked oc-minor in d_ws; conv loops index them wave-
//    uniformly -> s_load, weights ride the scalar pipe.
//  - conv1: lane=(cg,r), acc[6][4]; pools fused via shfl. conv2: lane=(r,c),
//    acc[16] oc-inner. FCs block-cooperative (1 weight load -> 4 images).
// ---------------------------------------------------------------------------

constexpr int THREADS = 256;
constexpr int IPB = 4;                  // images per block (1 per wave)

// per-image LDS offsets (floats)
constexpr int XS_OFF = 0;               // [3][19][20] = 1140
constexpr int P1_OFF = 0;               // [6][14][14] = 1176 (overwrites xs)
constexpr int P2_OFF = 1184;            // [400] flatten oc*25+r*5+c
constexpr int F1_OFF = 0;               // [120] (p1 dead after conv2)
constexpr int F2_OFF = 128;             // [84]
constexpr int IMG_STRIDE = 1584;
constexpr int LDS_FLOATS = IPB * IMG_STRIDE;   // 6336 floats -> 25344 B

__device__ __forceinline__ void wave_sync() {
    asm volatile("s_waitcnt lgkmcnt(0)" ::: "memory");
}

// ws[0..600)    = w1r[k=(ci*5+kr)*5+kc][8] (oc minor, 6 used, padded to 8)
// ws[600..3000) = w2r[k=(ci*5+kr)*5+kc][16] (oc minor)
__global__ void repack_weights(const float* __restrict__ w1,
                               const float* __restrict__ w2,
                               float* __restrict__ ws) {
    int t = blockIdx.x * 256 + threadIdx.x;
    if (t < 600) {
        int k = t >> 3, oc = t & 7;
        ws[t] = (oc < 6) ? w1[oc * 75 + k] : 0.f;
    } else if (t < 3000) {
        int u = t - 600;
        int k = u >> 4, oc = u & 15;
        ws[t] = w2[oc * 150 + k];
    }
}

extern "C" __global__ __launch_bounds__(THREADS, 3)
void lenet_fused(const float* __restrict__ x,
                 const float* __restrict__ wr,
                 const float* __restrict__ fc1w, const float* __restrict__ fc1b,
                 const float* __restrict__ fc2w, const float* __restrict__ fc2b,
                 const float* __restrict__ fc3w, const float* __restrict__ fc3b,
                 float* __restrict__ out)
{
    __shared__ __align__(16) float lds[LDS_FLOATS];
    const int tid  = threadIdx.x;
    const int lane = tid & 63;
    const int wv   = tid >> 6;
    const int img0 = blockIdx.x * IPB;

    float* base = lds + wv * IMG_STRIDE;

    // ---- stage input patch rows 0..18, cols 0..19 (per wave, float4) ----
    {
        const float4* xg = (const float4*)(x + (size_t)(img0 + wv) * 3072);
        float4* xs4 = (float4*)(base + XS_OFF);
        for (int i = lane; i < 285; i += 64) {       // 3ch * 19r * 5(f4)
            int c = i / 95, rem = i - c * 95;
            int r = rem / 5, c4 = rem - r * 5;
            xs4[i] = xg[c * 256 + r * 8 + c4];
        }
    }
    wave_sync();

    const float* xs = base + XS_OFF;
    float* p1 = base + P1_OFF;

    // ---- conv1 + relu + pool1 -> p1 [6][14][14] ----
    // lane = cg*16 + r ; cols 4cg..4cg+3 (cg3: 12..14 valid), rows 0..14.
    {
        const int r  = lane & 15;
        const int cg = lane >> 4;
        const int rr = (r < 15) ? r : 14;            // r==15 lanes duplicate row 14
        float acc[6][4];
        #pragma unroll
        for (int o = 0; o < 6; ++o)
            #pragma unroll
            for (int j = 0; j < 4; ++j) acc[o][j] = 0.f;

        #pragma unroll
        for (int ci = 0; ci < 3; ++ci) {
            #pragma unroll
            for (int kr = 0; kr < 5; ++kr) {
                const float* xrow = xs + ci * 380 + (rr + kr) * 20 + 4 * cg;
                float xv[8];
                #pragma unroll
                for (int j = 0; j < 8; ++j) xv[j] = xrow[j];
                const float* wk = wr + (ci * 5 + kr) * 5 * 8;   // uniform -> s_load
                #pragma unroll
                for (int kc = 0; kc < 5; ++kc) {
                    #pragma unroll
                    for (int o = 0; o < 6; ++o) {
                        const float w = wk[kc * 8 + o];
                        #pragma unroll
                        for (int j = 0; j < 4; ++j)
                            acc[o][j] = fmaf(xv[j + kc], w, acc[o][j]);
                    }
                }
            }
        }
        wave_sync();   // xs fully consumed; safe to overwrite with p1
        #pragma unroll
        for (int o = 0; o < 6; ++o) {
            float a[5];
            #pragma unroll
            for (int j = 0; j < 4; ++j) a[j] = fmaxf(acc[o][j], 0.f);
            a[4] = __shfl(a[0], lane + 16, 64);      // next cg's col0 (cg3: unused)
            float pm[4];
            #pragma unroll
            for (int j = 0; j < 4; ++j) pm[j] = fmaxf(a[j], a[j + 1]);
            float m[4];
            #pragma unroll
            for (int j = 0; j < 4; ++j)
                m[j] = fmaxf(pm[j], __shfl(pm[j], lane + 1, 64));   // row r+1
            if (r < 14) {
                float* d = p1 + o * 196 + r * 14 + 4 * cg;
                ((float2*)d)[0] = make_float2(m[0], m[1]);
                if (cg < 3) ((float2*)d)[1] = make_float2(m[2], m[3]);
            }
        }
    }
    wave_sync();

    // ---- conv2 + relu + pool2 -> p2 [16*5*5] flatten order ----
    float* p2 = base + P2_OFF;
    {
        const int l = (lane < 36) ? lane : 35;
        const int r = l / 6, c = l - r * 6;
        const float* w2r = wr + 600;
        float acc[16];
        #pragma unroll
        for (int o = 0; o < 16; ++o) acc[o] = 0.f;

        #pragma unroll
        for (int ci = 0; ci < 6; ++ci) {
            #pragma unroll
            for (int kr = 0; kr < 5; ++kr) {
                const float* prow = p1 + ci * 196 + (r + kr) * 14 + c;
                float xv[5];
                #pragma unroll
                for (int j = 0; j < 5; ++j) xv[j] = prow[j];
                const float* wk = w2r + (ci * 5 + kr) * 5 * 16;  // uniform -> s_load
                #pragma unroll
                for (int kc = 0; kc < 5; ++kc) {
                    #pragma unroll
                    for (int o = 0; o < 16; ++o)
                        acc[o] = fmaf(xv[kc], wk[kc * 16 + o], acc[o]);
                }
            }
        }
        #pragma unroll
        for (int o = 0; o < 16; ++o) {
            float a   = fmaxf(acc[o], 0.f);
            float pmv = fmaxf(a, __shfl(a, lane + 1, 64));      // col c+1
            float mv  = fmaxf(pmv, __shfl(pmv, lane + 6, 64));  // row r+1
            if (r < 5 && c < 5) p2[o * 25 + r * 5 + c] = mv;
        }
    }
    __syncthreads();   // all 4 images' p2 ready -> block-cooperative FCs

    // ---- fc1 (120x400) + relu : thread=row, one w load feeds 4 images ----
    if (tid < 120) {
        const int row = tid;
        const float4* wrow = (const float4*)(fc1w + row * 400);
        const float bz = fc1b[row];
        float acc0 = bz, acc1 = bz, acc2 = bz, acc3 = bz;
        const float4* a0p = (const float4*)(lds + 0 * IMG_STRIDE + P2_OFF);
        const float4* a1p = (const float4*)(lds + 1 * IMG_STRIDE + P2_OFF);
        const float4* a2p = (const float4*)(lds + 2 * IMG_STRIDE + P2_OFF);
        const float4* a3p = (const float4*)(lds + 3 * IMG_STRIDE + P2_OFF);
        #pragma unroll 2
        for (int k = 0; k < 100; ++k) {
            float4 w4 = wrow[k];
            float4 a0 = a0p[k], a1 = a1p[k], a2 = a2p[k], a3 = a3p[k];
            acc0 = fmaf(a0.x, w4.x, acc0); acc0 = fmaf(a0.y, w4.y, acc0);
            acc0 = fmaf(a0.z, w4.z, acc0); acc0 = fmaf(a0.w, w4.w, acc0);
            acc1 = fmaf(a1.x, w4.x, acc1); acc1 = fmaf(a1.y, w4.y, acc1);
            acc1 = fmaf(a1.z, w4.z, acc1); acc1 = fmaf(a1.w, w4.w, acc1);
            acc2 = fmaf(a2.x, w4.x, acc2); acc2 = fmaf(a2.y, w4.y, acc2);
            acc2 = fmaf(a2.z, w4.z, acc2); acc2 = fmaf(a2.w, w4.w, acc2);
            acc3 = fmaf(a3.x, w4.x, acc3); acc3 = fmaf(a3.y, w4.y, acc3);
            acc3 = fmaf(a3.z, w4.z, acc3); acc3 = fmaf(a3.w, w4.w, acc3);
        }
        lds[0 * IMG_STRIDE + F1_OFF + row] = fmaxf(acc0, 0.f);
        lds[1 * IMG_STRIDE + F1_OFF + row] = fmaxf(acc1, 0.f);
        lds[2 * IMG_STRIDE + F1_OFF + row] = fmaxf(acc2, 0.f);
        lds[3 * IMG_STRIDE + F1_OFF + row] = fmaxf(acc3, 0.f);
    }
    __syncthreads();

    // ---- fc2 (84x120) + relu ----
    if (tid < 84) {
        const int row = tid;
        const float4* wrow = (const float4*)(fc2w + row * 120);
        const float bz = fc2b[row];
        float acc0 = bz, acc1 = bz, acc2 = bz, acc3 = bz;
        const float4* f0 = (const float4*)(lds + 0 * IMG_STRIDE + F1_OFF);
        const float4* f1 = (const float4*)(lds + 1 * IMG_STRIDE + F1_OFF);
        const float4* f2 = (const float4*)(lds + 2 * IMG_STRIDE + F1_OFF);
        const float4* f3 = (const float4*)(lds + 3 * IMG_STRIDE + F1_OFF);
        #pragma unroll 2
        for (int k = 0; k < 30; ++k) {
            float4 w4 = wrow[k];
            float4 a0 = f0[k], a1 = f1[k], a2 = f2[k], a3 = f3[k];
            acc0 = fmaf(a0.x, w4.x, acc0); acc0 = fmaf(a0.y, w4.y, acc0);
            acc0 = fmaf(a0.z, w4.z, acc0); acc0 = fmaf(a0.w, w4.w, acc0);
            acc1 = fmaf(a1.x, w4.x, acc1); acc1 = fmaf(a1.y, w4.y, acc1);
            acc1 = fmaf(a1.z, w4.z, acc1); acc1 = fmaf(a1.w, w4.w, acc1);
            acc2 = fmaf(a2.x, w4.x, acc2); acc2 = fmaf(a2.y, w4.y, acc2);
            acc2 = fmaf(a2.z, w4.z, acc2); acc2 = fmaf(a2.w, w4.w, acc2);
            acc3 = fmaf(a3.x, w4.x, acc3); acc3 = fmaf(a3.y, w4.y, acc3);
            acc3 = fmaf(a3.z, w4.z, acc3); acc3 = fmaf(a3.w, w4.w, acc3);
        }
        lds[0 * IMG_STRIDE + F2_OFF + row] = fmaxf(acc0, 0.f);
        lds[1 * IMG_STRIDE + F2_OFF + row] = fmaxf(acc1, 0.f);
        lds[2 * IMG_STRIDE + F2_OFF + row] = fmaxf(acc2, 0.f);
        lds[3 * IMG_STRIDE + F2_OFF + row] = fmaxf(acc3, 0.f);
    }
    __syncthreads();

    // ---- fc3 (10x84) -> out ----
    if (tid < 40) {
        const int im  = tid / 10;
        const int row = tid - im * 10;
        const float4* wrow = (const float4*)(fc3w + row * 84);
        const float4* f2 = (const float4*)(lds + im * IMG_STRIDE + F2_OFF);
        float acc = fc3b[row];
        #pragma unroll
        for (int k = 0; k < 21; ++k) {
            float4 w4 = wrow[k];
            float4 a = f2[k];
            acc = fmaf(a.x, w4.x, acc); acc = fmaf(a.y, w4.y, acc);
            acc = fmaf(a.z, w4.z, acc); acc = fmaf(a.w, w4.w, acc);
        }
        out[(size_t)(img0 + im) * 10 + row] = acc;
    }
}

extern "C" void kernel_launch(void* const* d_in, const int* in_sizes, int n_in,
                              void* d_out, int out_size, void* d_ws, size_t ws_size,
                              hipStream_t stream) {
    const float* x    = (const float*)d_in[0];
    const float* w1   = (const float*)d_in[1];
    const float* w2   = (const float*)d_in[2];
    const float* fc1w = (const float*)d_in[3];
    const float* fc1b = (const float*)d_in[4];
    const float* fc2w = (const float*)d_in[5];
    const float* fc2b = (const float*)d_in[6];
    const float* fc3w = (const float*)d_in[7];
    const float* fc3b = (const float*)d_in[8];
    float* out = (float*)d_out;
    float* wr  = (float*)d_ws;               // 3000 floats = 12 KB

    repack_weights<<<12, 256, 0, stream>>>(w1, w2, wr);

    const int B = in_sizes[0] / 3072;        // 8192
    const int grid = B / IPB;                // 2048
    lenet_fused<<<grid, THREADS, 0, stream>>>(x, wr, fc1w, fc1b,
                                              fc2w, fc2b, fc3w, fc3b, out);
}

// Round 6
// 239.334 us; speedup vs baseline: 6.1458x; 4.4167x over previous
//
#include <hip/hip_runtime.h>

// ---------------------------------------------------------------------------
// Fused LeNet forward, round 6 = round-3 structure (best verified: 130 us)
// + packed fp32 math (v_pk_fma_f32 via float2 ext-vector builtins).
//  - REVERTED rounds 4/5: global "scalar-pipe" weights never scalarized ->
//    per-lane VMEM + spills. Weights live in LDS again.
//  - conv1: lane=(ocpair,row), v2f acc[15] packs the 2 output channels.
//  - conv2: lane=(ocpair,row), v2f acc[6] packs the 2 output channels.
//  - FCs pack adjacent k into v2f lanes (pairs come free from float4 loads).
//  - Pools fused in registers via shfl; 37 KB LDS -> 4 blocks/CU, (256,4).
// ---------------------------------------------------------------------------

typedef float v2f __attribute__((ext_vector_type(2)));

__device__ __forceinline__ v2f mk2(float a, float b) { v2f t; t.x = a; t.y = b; return t; }

constexpr int THREADS = 256;
constexpr int IPB = 4;                 // images per block (1 per wave)

// LDS layout (float offsets)
constexpr int W1_OFF = 0;              // conv1 w: 450
constexpr int W2_OFF = 452;            // conv2 w: 2400; reused as FC1 scratch
constexpr int IMG_BASE = 2852;
// per-image offsets:
constexpr int XS_OFF = 0;              // [3][19][20] = 1140
constexpr int P1_OFF = 0;              // [6][14][14] = 1176 (overwrites xs)
constexpr int P2_OFF = 1184;           // [400] flatten order oc*25+r*5+c
constexpr int F1_OFF = 0;              // [120] (overwrites p1, dead after conv2)
constexpr int F2_OFF = 128;            // [84]
constexpr int IMG_STRIDE = 1600;
constexpr int LDS_FLOATS = IMG_BASE + IPB * IMG_STRIDE;   // 9252 -> 37008 B

__device__ __forceinline__ void wave_sync() {
    asm volatile("s_waitcnt lgkmcnt(0)" ::: "memory");
}

extern "C" __global__ __launch_bounds__(THREADS, 4)
void lenet_fused(const float* __restrict__ x,
                 const float* __restrict__ w1,
                 const float* __restrict__ w2,
                 const float* __restrict__ fc1w, const float* __restrict__ fc1b,
                 const float* __restrict__ fc2w, const float* __restrict__ fc2b,
                 const float* __restrict__ fc3w, const float* __restrict__ fc3b,
                 float* __restrict__ out)
{
    __shared__ __align__(16) float lds[LDS_FLOATS];
    const int tid  = threadIdx.x;
    const int lane = tid & 63;
    const int wv   = tid >> 6;
    const int img0 = blockIdx.x * IPB;

    // ---- stage weights (block-wide, float4) ----
    {
        const float4* s1 = (const float4*)w1;
        float4* d1 = (float4*)(lds + W1_OFF);
        for (int i = tid; i < 112; i += THREADS) d1[i] = s1[i];
        if (tid < 2) lds[W1_OFF + 448 + tid] = w1[448 + tid];
        const float4* s2 = (const float4*)w2;
        float4* d2 = (float4*)(lds + W2_OFF);
        for (int i = tid; i < 600; i += THREADS) d2[i] = s2[i];
    }

    // ---- stage input patch rows 0..18, cols 0..19 (per wave, float4) ----
    float* base = lds + IMG_BASE + wv * IMG_STRIDE;
    {
        const float4* xg = (const float4*)(x + (size_t)(img0 + wv) * 3072);
        float4* xs4 = (float4*)(base + XS_OFF);
        for (int i = lane; i < 285; i += 64) {       // 3ch * 19r * 5(f4)
            int c = i / 95, rem = i - c * 95;
            int r = rem / 5, c4 = rem - r * 5;
            xs4[i] = xg[c * 256 + r * 8 + c4];
        }
    }
    __syncthreads();

    const float* xs  = base + XS_OFF;
    const float* w1s = lds + W1_OFF;
    float* p1 = base + P1_OFF;
    const v2f zero2 = mk2(0.f, 0.f);

    // ---- conv1 + relu + pool1 -> p1 [6][14][14] ----
    // lane -> (ocpair 0..2, row 0..14); lanes 45..63 duplicate lane 44 so all
    // 64 lanes execute the shfls. v2f packs the 2 output channels -> pk_fma.
    {
        const int l   = (lane < 45) ? lane : 44;
        const int ocp = l / 15;
        const int r   = l - ocp * 15;
        const int oc0 = ocp * 2;
        v2f acc[15];
        #pragma unroll
        for (int c = 0; c < 15; ++c) acc[c] = zero2;
        for (int ci = 0; ci < 3; ++ci) {
            #pragma unroll
            for (int kr = 0; kr < 5; ++kr) {
                const float* xrow = xs + ci * 380 + (r + kr) * 20;
                float xv[19];
                #pragma unroll
                for (int j = 0; j < 19; ++j) xv[j] = xrow[j];
                const float* wr0 = w1s + oc0 * 75 + ci * 25 + kr * 5;
                #pragma unroll
                for (int kc = 0; kc < 5; ++kc) {
                    const v2f wvv = mk2(wr0[kc], wr0[75 + kc]);
                    #pragma unroll
                    for (int c = 0; c < 15; ++c)
                        acc[c] = __builtin_elementwise_fma(
                            mk2(xv[c + kc], xv[c + kc]), wvv, acc[c]);
                }
            }
        }
        // relu + pairwise col max (packed over the 2 ocs)
        v2f pm[14];
        #pragma unroll
        for (int c = 0; c < 14; ++c)
            pm[c] = __builtin_elementwise_max(
                __builtin_elementwise_max(acc[c], acc[c + 1]), zero2);
        // neighbor row's pairwise max via shfl (all 64 lanes execute)
        v2f m[14];
        #pragma unroll
        for (int c = 0; c < 14; ++c) {
            m[c].x = fmaxf(pm[c].x, __shfl(pm[c].x, lane + 1, 64));
            m[c].y = fmaxf(pm[c].y, __shfl(pm[c].y, lane + 1, 64));
        }
        wave_sync();   // drain xs reads before overwriting region with p1
        if (r < 14) {  // lanes 45..63 have r==14 -> excluded
            float2* d0 = (float2*)(p1 + oc0 * 196 + r * 14);
            float2* d1 = (float2*)(p1 + (oc0 + 1) * 196 + r * 14);
            #pragma unroll
            for (int j = 0; j < 7; ++j) {
                d0[j] = make_float2(m[2 * j].x, m[2 * j + 1].x);
                d1[j] = make_float2(m[2 * j].y, m[2 * j + 1].y);
            }
        }
    }
    wave_sync();

    // ---- conv2 + relu + pool2 -> p2 [16*5*5] flatten order ----
    float* p2 = base + P2_OFF;
    const float* w2s = lds + W2_OFF;
    {
        const int l   = (lane < 48) ? lane : 47;
        const int ocp = l / 6;
        const int r   = l - ocp * 6;
        const int oc0 = ocp * 2;
        v2f acc[6];
        #pragma unroll
        for (int c = 0; c < 6; ++c) acc[c] = zero2;
        for (int ci = 0; ci < 6; ++ci) {
            #pragma unroll
            for (int kr = 0; kr < 5; ++kr) {
                const float* prow = p1 + ci * 196 + (r + kr) * 14;
                float xv[10];
                #pragma unroll
                for (int j = 0; j < 10; ++j) xv[j] = prow[j];
                const float* wr0 = w2s + oc0 * 150 + ci * 25 + kr * 5;
                #pragma unroll
                for (int kc = 0; kc < 5; ++kc) {
                    const v2f wvv = mk2(wr0[kc], wr0[150 + kc]);
                    #pragma unroll
                    for (int c = 0; c < 6; ++c)
                        acc[c] = __builtin_elementwise_fma(
                            mk2(xv[c + kc], xv[c + kc]), wvv, acc[c]);
                }
            }
        }
        v2f pm[5];
        #pragma unroll
        for (int c = 0; c < 5; ++c)
            pm[c] = __builtin_elementwise_max(
                __builtin_elementwise_max(acc[c], acc[c + 1]), zero2);
        v2f m[5];
        #pragma unroll
        for (int c = 0; c < 5; ++c) {
            m[c].x = fmaxf(pm[c].x, __shfl(pm[c].x, lane + 1, 64));
            m[c].y = fmaxf(pm[c].y, __shfl(pm[c].y, lane + 1, 64));
        }
        if (r < 5) {   // lanes 48..63 have r==5 -> excluded
            float* q0 = p2 + oc0 * 25 + r * 5;
            float* q1 = p2 + (oc0 + 1) * 25 + r * 5;
            #pragma unroll
            for (int c = 0; c < 5; ++c) { q0[c] = m[c].x; q1[c] = m[c].y; }
        }
    }
    __syncthreads();   // all images' p2 ready; w2 region becomes FC scratch

    // ---- fc1 (120x400) K-split x2: 240 threads, packed-k, partials->scratch ----
    float* scr = lds + W2_OFF;   // 960 floats
    if (tid < 240) {
        const int row  = tid >> 1;
        const int half = tid & 1;
        const float4* wrow = (const float4*)(fc1w + row * 400) + half * 50;
        const float4* a0p = (const float4*)(lds + IMG_BASE + 0 * IMG_STRIDE + P2_OFF) + half * 50;
        const float4* a1p = (const float4*)(lds + IMG_BASE + 1 * IMG_STRIDE + P2_OFF) + half * 50;
        const float4* a2p = (const float4*)(lds + IMG_BASE + 2 * IMG_STRIDE + P2_OFF) + half * 50;
        const float4* a3p = (const float4*)(lds + IMG_BASE + 3 * IMG_STRIDE + P2_OFF) + half * 50;
        v2f acc0 = zero2, acc1 = zero2, acc2 = zero2, acc3 = zero2;
        #pragma unroll 2
        for (int k = 0; k < 50; ++k) {
            float4 w4 = wrow[k];
            const v2f wxy = mk2(w4.x, w4.y), wzw = mk2(w4.z, w4.w);
            float4 a0 = a0p[k], a1 = a1p[k], a2 = a2p[k], a3 = a3p[k];
            acc0 = __builtin_elementwise_fma(mk2(a0.x, a0.y), wxy, acc0);
            acc0 = __builtin_elementwise_fma(mk2(a0.z, a0.w), wzw, acc0);
            acc1 = __builtin_elementwise_fma(mk2(a1.x, a1.y), wxy, acc1);
            acc1 = __builtin_elementwise_fma(mk2(a1.z, a1.w), wzw, acc1);
            acc2 = __builtin_elementwise_fma(mk2(a2.x, a2.y), wxy, acc2);
            acc2 = __builtin_elementwise_fma(mk2(a2.z, a2.w), wzw, acc2);
            acc3 = __builtin_elementwise_fma(mk2(a3.x, a3.y), wxy, acc3);
            acc3 = __builtin_elementwise_fma(mk2(a3.z, a3.w), wzw, acc3);
        }
        scr[0 * 240 + row * 2 + half] = acc0.x + acc0.y;
        scr[1 * 240 + row * 2 + half] = acc1.x + acc1.y;
        scr[2 * 240 + row * 2 + half] = acc2.x + acc2.y;
        scr[3 * 240 + row * 2 + half] = acc3.x + acc3.y;
    }
    __syncthreads();

    // ---- fc1 reduce + bias + relu -> f1 per image ----
    if (tid < 120) {
        const float b = fc1b[tid];
        #pragma unroll
        for (int im = 0; im < 4; ++im) {
            float v = scr[im * 240 + tid * 2] + scr[im * 240 + tid * 2 + 1] + b;
            lds[IMG_BASE + im * IMG_STRIDE + F1_OFF + tid] = fmaxf(v, 0.f);
        }
    }
    __syncthreads();

    // ---- fc2 (84x120) + relu, packed-k ----
    if (tid < 84) {
        const int row = tid;
        const float4* wrow = (const float4*)(fc2w + row * 120);
        const float bz = fc2b[row];
        v2f acc0 = zero2, acc1 = zero2, acc2 = zero2, acc3 = zero2;
        const float4* f0 = (const float4*)(lds + IMG_BASE + 0 * IMG_STRIDE + F1_OFF);
        const float4* f1 = (const float4*)(lds + IMG_BASE + 1 * IMG_STRIDE + F1_OFF);
        const float4* f2 = (const float4*)(lds + IMG_BASE + 2 * IMG_STRIDE + F1_OFF);
        const float4* f3 = (const float4*)(lds + IMG_BASE + 3 * IMG_STRIDE + F1_OFF);
        #pragma unroll 2
        for (int k = 0; k < 30; ++k) {
            float4 w4 = wrow[k];
            const v2f wxy = mk2(w4.x, w4.y), wzw = mk2(w4.z, w4.w);
            float4 a0 = f0[k], a1 = f1[k], a2 = f2[k], a3 = f3[k];
            acc0 = __builtin_elementwise_fma(mk2(a0.x, a0.y), wxy, acc0);
            acc0 = __builtin_elementwise_fma(mk2(a0.z, a0.w), wzw, acc0);
            acc1 = __builtin_elementwise_fma(mk2(a1.x, a1.y), wxy, acc1);
            acc1 = __builtin_elementwise_fma(mk2(a1.z, a1.w), wzw, acc1);
            acc2 = __builtin_elementwise_fma(mk2(a2.x, a2.y), wxy, acc2);
            acc2 = __builtin_elementwise_fma(mk2(a2.z, a2.w), wzw, acc2);
            acc3 = __builtin_elementwise_fma(mk2(a3.x, a3.y), wxy, acc3);
            acc3 = __builtin_elementwise_fma(mk2(a3.z, a3.w), wzw, acc3);
        }
        lds[IMG_BASE + 0 * IMG_STRIDE + F2_OFF + row] = fmaxf(acc0.x + acc0.y + bz, 0.f);
        lds[IMG_BASE + 1 * IMG_STRIDE + F2_OFF + row] = fmaxf(acc1.x + acc1.y + bz, 0.f);
        lds[IMG_BASE + 2 * IMG_STRIDE + F2_OFF + row] = fmaxf(acc2.x + acc2.y + bz, 0.f);
        lds[IMG_BASE + 3 * IMG_STRIDE + F2_OFF + row] = fmaxf(acc3.x + acc3.y + bz, 0.f);
    }
    __syncthreads();

    // ---- fc3 (10x84) -> out, packed-k ----
    if (tid < 40) {
        const int im  = tid / 10;
        const int row = tid - im * 10;
        const float4* wrow = (const float4*)(fc3w + row * 84);
        const float4* f2 = (const float4*)(lds + IMG_BASE + im * IMG_STRIDE + F2_OFF);
        v2f acc = zero2;
        #pragma unroll
        for (int k = 0; k < 21; ++k) {
            float4 w4 = wrow[k];
            float4 a = f2[k];
            acc = __builtin_elementwise_fma(mk2(a.x, a.y), mk2(w4.x, w4.y), acc);
            acc = __builtin_elementwise_fma(mk2(a.z, a.w), mk2(w4.z, w4.w), acc);
        }
        out[(size_t)(img0 + im) * 10 + row] = acc.x + acc.y + fc3b[row];
    }
}

extern "C" void kernel_launch(void* const* d_in, const int* in_sizes, int n_in,
                              void* d_out, int out_size, void* d_ws, size_t ws_size,
                              hipStream_t stream) {
    const float* x    = (const float*)d_in[0];
    const float* w1   = (const float*)d_in[1];
    const float* w2   = (const float*)d_in[2];
    const float* fc1w = (const float*)d_in[3];
    const float* fc1b = (const float*)d_in[4];
    const float* fc2w = (const float*)d_in[5];
    const float* fc2b = (const float*)d_in[6];
    const float* fc3w = (const float*)d_in[7];
    const float* fc3b = (const float*)d_in[8];
    float* out = (float*)d_out;

    const int B = in_sizes[0] / 3072;       // 8192
    const int grid = B / IPB;               // 2048
    lenet_fused<<<grid, THREADS, 0, stream>>>(x, w1, w2, fc1w, fc1b,
                                              fc2w, fc2b, fc3w, fc3b, out);
}

// Round 7
// 234.739 us; speedup vs baseline: 6.2661x; 1.0196x over previous
//
#include <hip/hip_runtime.h>

// ---------------------------------------------------------------------------
// Fused LeNet forward, round 7.
//  - DEEPER top-left exploit: conv2 only reads p1[0..9][0..9] -> pool1 10x10
//    -> conv1 only 11x11 output -> x patch 15x15. Conv1 FLOPs -19%.
//  - Software-pipelined conv loops: next (ci,kr) x-row + weights prefetched
//    into regs while current FMAs issue (attacks LDS latency stall).
//  - Weights repacked oc-pair-minor (v2f) in LDS: 1 ds_read_b64 per (kc,ocp),
//    wave-uniform address -> broadcast, no conflicts.
//  - xs rows 20 floats (bank-clean), p1 rows 12 (16B-aligned, 2-way max).
//  - IMG_STRIDE 1300 (%32=4) -> fc1/fc2 4-image streams bank-disjoint.
//  - LDS 32.2 KB, launch_bounds(256,4) (VGPR cap 128, no spill risk).
// ---------------------------------------------------------------------------

typedef float v2f __attribute__((ext_vector_type(2)));
__device__ __forceinline__ v2f mk2(float a, float b) { v2f t; t.x = a; t.y = b; return t; }
__device__ __forceinline__ v2f shfl2(v2f v, int src) {
    v2f r; r.x = __shfl(v.x, src, 64); r.y = __shfl(v.y, src, 64); return r;
}

constexpr int THREADS = 256;
constexpr int IPB = 4;                 // images per block (1 per wave)

// LDS layout (float offsets)
constexpr int W1P_OFF = 0;             // conv1 w packed [ocp0..2][k0..74][2] = 450
constexpr int W2P_OFF = 452;           // conv2 w packed [ocp0..7][k0..149][2] = 2400
constexpr int IMG_BASE = 2852;
// per-image offsets:
constexpr int XS_OFF = 0;              // [3][15][20] = 900
constexpr int P1_OFF = 0;              // [6][10][12] = 720 (overwrites xs)
constexpr int P2_OFF = 900;            // [400] flatten oc*25+r*5+c
constexpr int F1_OFF = 0;              // [120] (p1 dead after conv2)
constexpr int F2_OFF = 128;            // [84]
constexpr int IMG_STRIDE = 1300;       // 16B-aligned; %32==4 bank skew
constexpr int LDS_FLOATS = IMG_BASE + IPB * IMG_STRIDE;   // 8052 -> 32208 B

__device__ __forceinline__ void wave_sync() {
    asm volatile("s_waitcnt lgkmcnt(0)" ::: "memory");
}

extern "C" __global__ __launch_bounds__(THREADS, 4)
void lenet_fused(const float* __restrict__ x,
                 const float* __restrict__ w1,
                 const float* __restrict__ w2,
                 const float* __restrict__ fc1w, const float* __restrict__ fc1b,
                 const float* __restrict__ fc2w, const float* __restrict__ fc2b,
                 const float* __restrict__ fc3w, const float* __restrict__ fc3b,
                 float* __restrict__ out)
{
    __shared__ __align__(16) float lds[LDS_FLOATS];
    const int tid  = threadIdx.x;
    const int lane = tid & 63;
    const int wv   = tid >> 6;
    const int img0 = blockIdx.x * IPB;
    const v2f zero2 = mk2(0.f, 0.f);

    // ---- stage weights, repacked oc-pair-minor ----
    for (int i = tid; i < 450; i += THREADS) {
        int ocp = i / 150, rem = i - ocp * 150, k = rem >> 1, h = rem & 1;
        lds[W1P_OFF + i] = w1[(2 * ocp + h) * 75 + k];
    }
    for (int i = tid; i < 2400; i += THREADS) {
        int ocp = i / 300, rem = i - ocp * 300, k = rem >> 1, h = rem & 1;
        lds[W2P_OFF + i] = w2[(2 * ocp + h) * 150 + k];
    }

    // ---- stage input patch rows 0..14, cols 0..19 (per wave, float4) ----
    float* base = lds + IMG_BASE + wv * IMG_STRIDE;
    {
        const float4* xg = (const float4*)(x + (size_t)(img0 + wv) * 3072);
        float4* xs4 = (float4*)(base + XS_OFF);
        for (int i = lane; i < 225; i += 64) {       // 3ch * 15r * 5(f4)
            int c = i / 75, rem = i - c * 75;
            int r = rem / 5, c4 = rem - r * 5;
            xs4[i] = xg[c * 256 + r * 8 + c4];
        }
    }
    __syncthreads();

    float* p1 = base + P1_OFF;

    // ---- conv1 + relu + pool1 -> p1 [6][10][12] ----
    // lane -> (ocp 0..2, r 0..10); 33 active, dups harmless. Pipelined.
    {
        const int l   = (lane < 33) ? lane : 32;
        const int ocp = l / 11;
        const int r   = l - ocp * 11;
        const float4* xs4 = (const float4*)(base + XS_OFF);
        const v2f* w1p = (const v2f*)(lds + W1P_OFF);

        v2f acc[11];
        #pragma unroll
        for (int c = 0; c < 11; ++c) acc[c] = zero2;

        float4 Xa = xs4[r * 5 + 0], Xb = xs4[r * 5 + 1],
               Xc = xs4[r * 5 + 2], Xd = xs4[r * 5 + 3];
        v2f W0[5];
        #pragma unroll
        for (int kc = 0; kc < 5; ++kc) W0[kc] = w1p[ocp * 75 + kc];

        #pragma unroll
        for (int i = 0; i < 15; ++i) {
            float4 Na, Nb, Nc, Nd; v2f W1r[5];
            if (i < 14) {                              // prefetch i+1
                const int ci = (i + 1) / 5, kr = (i + 1) % 5;
                const int b = ci * 75 + (r + kr) * 5;
                Na = xs4[b]; Nb = xs4[b + 1]; Nc = xs4[b + 2]; Nd = xs4[b + 3];
                #pragma unroll
                for (int kc = 0; kc < 5; ++kc)
                    W1r[kc] = w1p[ocp * 75 + (i + 1) * 5 + kc];
            }
            float xv[16];
            xv[0]=Xa.x; xv[1]=Xa.y; xv[2]=Xa.z;  xv[3]=Xa.w;
            xv[4]=Xb.x; xv[5]=Xb.y; xv[6]=Xb.z;  xv[7]=Xb.w;
            xv[8]=Xc.x; xv[9]=Xc.y; xv[10]=Xc.z; xv[11]=Xc.w;
            xv[12]=Xd.x; xv[13]=Xd.y; xv[14]=Xd.z; xv[15]=Xd.w;
            #pragma unroll
            for (int kc = 0; kc < 5; ++kc)
                #pragma unroll
                for (int c = 0; c < 11; ++c)
                    acc[c] = __builtin_elementwise_fma(
                        mk2(xv[c + kc], xv[c + kc]), W0[kc], acc[c]);
            if (i < 14) {
                Xa = Na; Xb = Nb; Xc = Nc; Xd = Nd;
                #pragma unroll
                for (int kc = 0; kc < 5; ++kc) W0[kc] = W1r[kc];
            }
        }

        // relu + 2x2 stride-1 pool (packed over oc pair)
        v2f a[11], pm[10], m[10];
        #pragma unroll
        for (int c = 0; c < 11; ++c) a[c] = __builtin_elementwise_max(acc[c], zero2);
        #pragma unroll
        for (int c = 0; c < 10; ++c) pm[c] = __builtin_elementwise_max(a[c], a[c + 1]);
        #pragma unroll
        for (int c = 0; c < 10; ++c)
            m[c] = __builtin_elementwise_max(pm[c], shfl2(pm[c], lane + 1));  // row r+1
        wave_sync();   // xs reads drained before overwriting region with p1
        if (r < 10) {
            const int oc0 = ocp * 2;
            float2* d0 = (float2*)(p1 + oc0 * 120 + r * 12);
            float2* d1 = (float2*)(p1 + (oc0 + 1) * 120 + r * 12);
            #pragma unroll
            for (int j = 0; j < 5; ++j) {
                d0[j] = make_float2(m[2 * j].x, m[2 * j + 1].x);
                d1[j] = make_float2(m[2 * j].y, m[2 * j + 1].y);
            }
        }
    }
    wave_sync();

    // ---- conv2 + relu + pool2 -> p2 [16*5*5] flatten order ----
    float* p2 = base + P2_OFF;
    {
        const int l   = (lane < 48) ? lane : 47;
        const int ocp = l / 6;
        const int r   = l - ocp * 6;
        const float4* p14 = (const float4*)p1;
        const float2* p12 = (const float2*)p1;
        const v2f* w2p = (const v2f*)(lds + W2P_OFF);

        v2f acc[6];
        #pragma unroll
        for (int c = 0; c < 6; ++c) acc[c] = zero2;

        float4 Xa = p14[r * 3 + 0], Xb = p14[r * 3 + 1];
        float2 Xc = p12[r * 6 + 4];
        v2f W0[5];
        #pragma unroll
        for (int kc = 0; kc < 5; ++kc) W0[kc] = w2p[ocp * 150 + kc];

        #pragma unroll
        for (int i = 0; i < 30; ++i) {
            float4 Na, Nb; float2 Nc; v2f W1r[5];
            if (i < 29) {                              // prefetch i+1
                const int ci = (i + 1) / 5, kr = (i + 1) % 5;
                Na = p14[ci * 30 + (r + kr) * 3 + 0];
                Nb = p14[ci * 30 + (r + kr) * 3 + 1];
                Nc = p12[ci * 60 + (r + kr) * 6 + 4];
                #pragma unroll
                for (int kc = 0; kc < 5; ++kc)
                    W1r[kc] = w2p[ocp * 150 + (i + 1) * 5 + kc];
            }
            float xv[10];
            xv[0]=Xa.x; xv[1]=Xa.y; xv[2]=Xa.z; xv[3]=Xa.w;
            xv[4]=Xb.x; xv[5]=Xb.y; xv[6]=Xb.z; xv[7]=Xb.w;
            xv[8]=Xc.x; xv[9]=Xc.y;
            #pragma unroll
            for (int kc = 0; kc < 5; ++kc)
                #pragma unroll
                for (int c = 0; c < 6; ++c)
                    acc[c] = __builtin_elementwise_fma(
                        mk2(xv[c + kc], xv[c + kc]), W0[kc], acc[c]);
            if (i < 29) {
                Xa = Na; Xb = Nb; Xc = Nc;
                #pragma unroll
                for (int kc = 0; kc < 5; ++kc) W0[kc] = W1r[kc];
            }
        }

        v2f a[6], pm[5], m[5];
        #pragma unroll
        for (int c = 0; c < 6; ++c) a[c] = __builtin_elementwise_max(acc[c], zero2);
        #pragma unroll
        for (int c = 0; c < 5; ++c) pm[c] = __builtin_elementwise_max(a[c], a[c + 1]);
        #pragma unroll
        for (int c = 0; c < 5; ++c)
            m[c] = __builtin_elementwise_max(pm[c], shfl2(pm[c], lane + 1));  // row r+1
        if (r < 5) {
            const int oc0 = ocp * 2;
            #pragma unroll
            for (int c = 0; c < 5; ++c) {
                p2[oc0 * 25 + r * 5 + c]       = m[c].x;
                p2[(oc0 + 1) * 25 + r * 5 + c] = m[c].y;
            }
        }
    }
    __syncthreads();   // all images' p2 ready; w2p region becomes FC scratch

    // ---- fc1 (120x400) K-split x2: 240 threads, packed-k, partials->scratch ----
    float* scr = lds + W2P_OFF;   // 960 floats
    if (tid < 240) {
        const int row  = tid >> 1;
        const int half = tid & 1;
        const float4* wrow = (const float4*)(fc1w + row * 400) + half * 50;
        const float4* a0p = (const float4*)(lds + IMG_BASE + 0 * IMG_STRIDE + P2_OFF) + half * 50;
        const float4* a1p = (const float4*)(lds + IMG_BASE + 1 * IMG_STRIDE + P2_OFF) + half * 50;
        const float4* a2p = (const float4*)(lds + IMG_BASE + 2 * IMG_STRIDE + P2_OFF) + half * 50;
        const float4* a3p = (const float4*)(lds + IMG_BASE + 3 * IMG_STRIDE + P2_OFF) + half * 50;
        v2f acc0 = zero2, acc1 = zero2, acc2 = zero2, acc3 = zero2;
        #pragma unroll 4
        for (int k = 0; k < 50; ++k) {
            float4 w4 = wrow[k];
            const v2f wxy = mk2(w4.x, w4.y), wzw = mk2(w4.z, w4.w);
            float4 a0 = a0p[k], a1 = a1p[k], a2 = a2p[k], a3 = a3p[k];
            acc0 = __builtin_elementwise_fma(mk2(a0.x, a0.y), wxy, acc0);
            acc0 = __builtin_elementwise_fma(mk2(a0.z, a0.w), wzw, acc0);
            acc1 = __builtin_elementwise_fma(mk2(a1.x, a1.y), wxy, acc1);
            acc1 = __builtin_elementwise_fma(mk2(a1.z, a1.w), wzw, acc1);
            acc2 = __builtin_elementwise_fma(mk2(a2.x, a2.y), wxy, acc2);
            acc2 = __builtin_elementwise_fma(mk2(a2.z, a2.w), wzw, acc2);
            acc3 = __builtin_elementwise_fma(mk2(a3.x, a3.y), wxy, acc3);
            acc3 = __builtin_elementwise_fma(mk2(a3.z, a3.w), wzw, acc3);
        }
        scr[0 * 240 + row * 2 + half] = acc0.x + acc0.y;
        scr[1 * 240 + row * 2 + half] = acc1.x + acc1.y;
        scr[2 * 240 + row * 2 + half] = acc2.x + acc2.y;
        scr[3 * 240 + row * 2 + half] = acc3.x + acc3.y;
    }
    __syncthreads();

    // ---- fc1 reduce + bias + relu -> f1 per image ----
    if (tid < 120) {
        const float b = fc1b[tid];
        #pragma unroll
        for (int im = 0; im < 4; ++im) {
            float v = scr[im * 240 + tid * 2] + scr[im * 240 + tid * 2 + 1] + b;
            lds[IMG_BASE + im * IMG_STRIDE + F1_OFF + tid] = fmaxf(v, 0.f);
        }
    }
    __syncthreads();

    // ---- fc2 (84x120) + relu, packed-k ----
    if (tid < 84) {
        const int row = tid;
        const float4* wrow = (const float4*)(fc2w + row * 120);
        const float bz = fc2b[row];
        v2f acc0 = zero2, acc1 = zero2, acc2 = zero2, acc3 = zero2;
        const float4* f0 = (const float4*)(lds + IMG_BASE + 0 * IMG_STRIDE + F1_OFF);
        const float4* f1 = (const float4*)(lds + IMG_BASE + 1 * IMG_STRIDE + F1_OFF);
        const float4* f2 = (const float4*)(lds + IMG_BASE + 2 * IMG_STRIDE + F1_OFF);
        const float4* f3 = (const float4*)(lds + IMG_BASE + 3 * IMG_STRIDE + F1_OFF);
        #pragma unroll 2
        for (int k = 0; k < 30; ++k) {
            float4 w4 = wrow[k];
            const v2f wxy = mk2(w4.x, w4.y), wzw = mk2(w4.z, w4.w);
            float4 a0 = f0[k], a1 = f1[k], a2 = f2[k], a3 = f3[k];
            acc0 = __builtin_elementwise_fma(mk2(a0.x, a0.y), wxy, acc0);
            acc0 = __builtin_elementwise_fma(mk2(a0.z, a0.w), wzw, acc0);
            acc1 = __builtin_elementwise_fma(mk2(a1.x, a1.y), wxy, acc1);
            acc1 = __builtin_elementwise_fma(mk2(a1.z, a1.w), wzw, acc1);
            acc2 = __builtin_elementwise_fma(mk2(a2.x, a2.y), wxy, acc2);
            acc2 = __builtin_elementwise_fma(mk2(a2.z, a2.w), wzw, acc2);
            acc3 = __builtin_elementwise_fma(mk2(a3.x, a3.y), wxy, acc3);
            acc3 = __builtin_elementwise_fma(mk2(a3.z, a3.w), wzw, acc3);
        }
        lds[IMG_BASE + 0 * IMG_STRIDE + F2_OFF + row] = fmaxf(acc0.x + acc0.y + bz, 0.f);
        lds[IMG_BASE + 1 * IMG_STRIDE + F2_OFF + row] = fmaxf(acc1.x + acc1.y + bz, 0.f);
        lds[IMG_BASE + 2 * IMG_STRIDE + F2_OFF + row] = fmaxf(acc2.x + acc2.y + bz, 0.f);
        lds[IMG_BASE + 3 * IMG_STRIDE + F2_OFF + row] = fmaxf(acc3.x + acc3.y + bz, 0.f);
    }
    __syncthreads();

    // ---- fc3 (10x84) -> out, packed-k ----
    if (tid < 40) {
        const int im  = tid / 10;
        const int row = tid - im * 10;
        const float4* wrow = (const float4*)(fc3w + row * 84);
        const float4* f2 = (const float4*)(lds + IMG_BASE + im * IMG_STRIDE + F2_OFF);
        v2f acc = zero2;
        #pragma unroll
        for (int k = 0; k < 21; ++k) {
            float4 w4 = wrow[k];
            float4 a = f2[k];
            acc = __builtin_elementwise_fma(mk2(a.x, a.y), mk2(w4.x, w4.y), acc);
            acc = __builtin_elementwise_fma(mk2(a.z, a.w), mk2(w4.z, w4.w), acc);
        }
        out[(size_t)(img0 + im) * 10 + row] = acc.x + acc.y + fc3b[row];
    }
}

extern "C" void kernel_launch(void* const* d_in, const int* in_sizes, int n_in,
                              void* d_out, int out_size, void* d_ws, size_t ws_size,
                              hipStream_t stream) {
    const float* x    = (const float*)d_in[0];
    const float* w1   = (const float*)d_in[1];
    const float* w2   = (const float*)d_in[2];
    const float* fc1w = (const float*)d_in[3];
    const float* fc1b = (const float*)d_in[4];
    const float* fc2w = (const float*)d_in[5];
    const float* fc2b = (const float*)d_in[6];
    const float* fc3w = (const float*)d_in[7];
    const float* fc3b = (const float*)d_in[8];
    float* out = (float*)d_out;

    const int B = in_sizes[0] / 3072;       // 8192
    const int grid = B / IPB;               // 2048
    lenet_fused<<<grid, THREADS, 0, stream>>>(x, w1, w2, fc1w, fc1b,
                                              fc2w, fc2b, fc3w, fc3b, out);
}

// Round 8
// 215.850 us; speedup vs baseline: 6.8144x; 1.0875x over previous
//
#include <hip/hip_runtime.h>

// ---------------------------------------------------------------------------
// Fused LeNet forward, round 8: ILP-2 (two images per wave).
//  - Each wave owns 2 images: two independent FMA streams per lane hide
//    LDS latency; conv weight loads (wave-uniform v2f) are shared by both.
//  - FC section: 8 images per block -> 16 pk_fma per fc-weight load.
//  - LDS per image 1120 fl (p2 overlaps dead xs tail) -> 47.2 KB block,
//    3 blocks/CU. launch_bounds(256,2) caps VGPR at 128 (~100 needed;
//    round-4 lesson: never under-cap, spill costs 10x).
//  - Reduced-extent convs (11x11 conv1 / 15x15 patch) kept from round 7.
// ---------------------------------------------------------------------------

typedef float v2f __attribute__((ext_vector_type(2)));
__device__ __forceinline__ v2f mk2(float a, float b) { v2f t; t.x = a; t.y = b; return t; }
__device__ __forceinline__ v2f shfl2(v2f v, int src) {
    v2f r; r.x = __shfl(v.x, src, 64); r.y = __shfl(v.y, src, 64); return r;
}

constexpr int THREADS = 256;
constexpr int IPB = 8;                 // images per block (2 per wave)

// LDS layout (float offsets)
constexpr int W1P_OFF = 0;             // conv1 w packed [ocp0..2][k0..74][2] = 450
constexpr int W2P_OFF = 452;           // conv2 w packed [ocp0..7][k0..149][2] = 2400
constexpr int IMG_BASE = 2852;
// per-image offsets:
constexpr int XS_OFF = 0;              // [3][15][20] = 900
constexpr int P1_OFF = 0;              // [6][10][12] = 720 (overwrites xs head)
constexpr int P2_OFF = 720;            // [400] in dead xs tail region
constexpr int F1_OFF = 0;              // [120] (p1 dead after conv2)
constexpr int F2_OFF = 128;            // [84]
constexpr int IMG_STRIDE = 1120;
constexpr int LDS_FLOATS = IMG_BASE + IPB * IMG_STRIDE;   // 11812 -> 47248 B

__device__ __forceinline__ void wave_sync() {
    asm volatile("s_waitcnt lgkmcnt(0)" ::: "memory");
}

extern "C" __global__ __launch_bounds__(THREADS, 2)
void lenet_fused(const float* __restrict__ x,
                 const float* __restrict__ w1,
                 const float* __restrict__ w2,
                 const float* __restrict__ fc1w, const float* __restrict__ fc1b,
                 const float* __restrict__ fc2w, const float* __restrict__ fc2b,
                 const float* __restrict__ fc3w, const float* __restrict__ fc3b,
                 float* __restrict__ out)
{
    __shared__ __align__(16) float lds[LDS_FLOATS];
    const int tid  = threadIdx.x;
    const int lane = tid & 63;
    const int wv   = tid >> 6;
    const int img0 = blockIdx.x * IPB;
    const v2f zero2 = mk2(0.f, 0.f);

    // ---- stage weights, repacked oc-pair-minor (block-wide) ----
    for (int i = tid; i < 450; i += THREADS) {
        int ocp = i / 150, rem = i - ocp * 150, k = rem >> 1, h = rem & 1;
        lds[W1P_OFF + i] = w1[(2 * ocp + h) * 75 + k];
    }
    for (int i = tid; i < 2400; i += THREADS) {
        int ocp = i / 300, rem = i - ocp * 300, k = rem >> 1, h = rem & 1;
        lds[W2P_OFF + i] = w2[(2 * ocp + h) * 150 + k];
    }

    // ---- stage input patches rows 0..14, cols 0..19 (2 images per wave) ----
    float* baseA = lds + IMG_BASE + (wv * 2) * IMG_STRIDE;
    float* baseB = baseA + IMG_STRIDE;
    {
        const float4* xgA = (const float4*)(x + (size_t)(img0 + wv * 2) * 3072);
        const float4* xgB = (const float4*)(x + (size_t)(img0 + wv * 2 + 1) * 3072);
        float4* dA = (float4*)(baseA + XS_OFF);
        float4* dB = (float4*)(baseB + XS_OFF);
        for (int i = lane; i < 225; i += 64) {       // 3ch * 15r * 5(f4)
            int c = i / 75, rem = i - c * 75;
            int r = rem / 5, c4 = rem - r * 5;
            int src = c * 256 + r * 8 + c4;
            dA[i] = xgA[src];
            dB[i] = xgB[src];
        }
    }
    __syncthreads();   // weights + staging visible

    float* p1A = baseA + P1_OFF;
    float* p1B = baseB + P1_OFF;

    // ---- conv1 + relu + pool1 -> p1 [6][10][12], both images ----
    // lane -> (ocp 0..2, r 0..10); 33 active, dup lanes guarded at store.
    {
        const int l   = (lane < 33) ? lane : 32;
        const int ocp = l / 11;
        const int r   = l - ocp * 11;
        const float4* xsA = (const float4*)(baseA + XS_OFF);
        const float4* xsB = (const float4*)(baseB + XS_OFF);
        const v2f* w1p = (const v2f*)(lds + W1P_OFF);

        v2f accA[11], accB[11];
        #pragma unroll
        for (int c = 0; c < 11; ++c) { accA[c] = zero2; accB[c] = zero2; }

        #pragma unroll
        for (int i = 0; i < 15; ++i) {
            const int ci = i / 5, kr = i - ci * 5;
            const int b = ci * 75 + (r + kr) * 5;
            float4 A0 = xsA[b], A1 = xsA[b + 1], A2 = xsA[b + 2], A3 = xsA[b + 3];
            float4 B0 = xsB[b], B1 = xsB[b + 1], B2 = xsB[b + 2], B3 = xsB[b + 3];
            v2f W[5];
            #pragma unroll
            for (int kc = 0; kc < 5; ++kc) W[kc] = w1p[ocp * 75 + i * 5 + kc];
            float xa[16], xb[16];
            xa[0]=A0.x; xa[1]=A0.y; xa[2]=A0.z;  xa[3]=A0.w;
            xa[4]=A1.x; xa[5]=A1.y; xa[6]=A1.z;  xa[7]=A1.w;
            xa[8]=A2.x; xa[9]=A2.y; xa[10]=A2.z; xa[11]=A2.w;
            xa[12]=A3.x; xa[13]=A3.y; xa[14]=A3.z; xa[15]=A3.w;
            xb[0]=B0.x; xb[1]=B0.y; xb[2]=B0.z;  xb[3]=B0.w;
            xb[4]=B1.x; xb[5]=B1.y; xb[6]=B1.z;  xb[7]=B1.w;
            xb[8]=B2.x; xb[9]=B2.y; xb[10]=B2.z; xb[11]=B2.w;
            xb[12]=B3.x; xb[13]=B3.y; xb[14]=B3.z; xb[15]=B3.w;
            #pragma unroll
            for (int kc = 0; kc < 5; ++kc) {
                #pragma unroll
                for (int c = 0; c < 11; ++c) {
                    accA[c] = __builtin_elementwise_fma(
                        mk2(xa[c + kc], xa[c + kc]), W[kc], accA[c]);
                    accB[c] = __builtin_elementwise_fma(
                        mk2(xb[c + kc], xb[c + kc]), W[kc], accB[c]);
                }
            }
        }

        // relu + 2x2 stride-1 pool (packed over oc pair), both images
        v2f pmA[10], pmB[10], mA[10], mB[10];
        #pragma unroll
        for (int c = 0; c < 10; ++c) {
            v2f aA0 = __builtin_elementwise_max(accA[c], zero2);
            v2f aA1 = __builtin_elementwise_max(accA[c + 1], zero2);
            pmA[c] = __builtin_elementwise_max(aA0, aA1);
            v2f aB0 = __builtin_elementwise_max(accB[c], zero2);
            v2f aB1 = __builtin_elementwise_max(accB[c + 1], zero2);
            pmB[c] = __builtin_elementwise_max(aB0, aB1);
        }
        #pragma unroll
        for (int c = 0; c < 10; ++c) {
            mA[c] = __builtin_elementwise_max(pmA[c], shfl2(pmA[c], lane + 1));
            mB[c] = __builtin_elementwise_max(pmB[c], shfl2(pmB[c], lane + 1));
        }
        wave_sync();   // xs reads drained before overwriting region with p1
        if (r < 10) {
            const int oc0 = ocp * 2;
            float2* dA0 = (float2*)(p1A + oc0 * 120 + r * 12);
            float2* dA1 = (float2*)(p1A + (oc0 + 1) * 120 + r * 12);
            float2* dB0 = (float2*)(p1B + oc0 * 120 + r * 12);
            float2* dB1 = (float2*)(p1B + (oc0 + 1) * 120 + r * 12);
            #pragma unroll
            for (int j = 0; j < 5; ++j) {
                dA0[j] = make_float2(mA[2 * j].x, mA[2 * j + 1].x);
                dA1[j] = make_float2(mA[2 * j].y, mA[2 * j + 1].y);
                dB0[j] = make_float2(mB[2 * j].x, mB[2 * j + 1].x);
                dB1[j] = make_float2(mB[2 * j].y, mB[2 * j + 1].y);
            }
        }
    }
    wave_sync();

    // ---- conv2 + relu + pool2 -> p2 [16*5*5] flatten order, both images ----
    float* p2A = baseA + P2_OFF;
    float* p2B = baseB + P2_OFF;
    {
        const int l   = (lane < 48) ? lane : 47;
        const int ocp = l / 6;
        const int r   = l - ocp * 6;
        const float4* pA4 = (const float4*)p1A;
        const float2* pA2 = (const float2*)p1A;
        const float4* pB4 = (const float4*)p1B;
        const float2* pB2 = (const float2*)p1B;
        const v2f* w2p = (const v2f*)(lds + W2P_OFF);

        v2f accA[6], accB[6];
        #pragma unroll
        for (int c = 0; c < 6; ++c) { accA[c] = zero2; accB[c] = zero2; }

        #pragma unroll
        for (int i = 0; i < 30; ++i) {
            const int ci = i / 5, kr = i - ci * 5;
            float4 A0 = pA4[ci * 30 + (r + kr) * 3 + 0];
            float4 A1 = pA4[ci * 30 + (r + kr) * 3 + 1];
            float2 A2 = pA2[ci * 60 + (r + kr) * 6 + 4];
            float4 B0 = pB4[ci * 30 + (r + kr) * 3 + 0];
            float4 B1 = pB4[ci * 30 + (r + kr) * 3 + 1];
            float2 B2 = pB2[ci * 60 + (r + kr) * 6 + 4];
            v2f W[5];
            #pragma unroll
            for (int kc = 0; kc < 5; ++kc) W[kc] = w2p[ocp * 150 + i * 5 + kc];
            float xa[10], xb[10];
            xa[0]=A0.x; xa[1]=A0.y; xa[2]=A0.z; xa[3]=A0.w;
            xa[4]=A1.x; xa[5]=A1.y; xa[6]=A1.z; xa[7]=A1.w;
            xa[8]=A2.x; xa[9]=A2.y;
            xb[0]=B0.x; xb[1]=B0.y; xb[2]=B0.z; xb[3]=B0.w;
            xb[4]=B1.x; xb[5]=B1.y; xb[6]=B1.z; xb[7]=B1.w;
            xb[8]=B2.x; xb[9]=B2.y;
            #pragma unroll
            for (int kc = 0; kc < 5; ++kc) {
                #pragma unroll
                for (int c = 0; c < 6; ++c) {
                    accA[c] = __builtin_elementwise_fma(
                        mk2(xa[c + kc], xa[c + kc]), W[kc], accA[c]);
                    accB[c] = __builtin_elementwise_fma(
                        mk2(xb[c + kc], xb[c + kc]), W[kc], accB[c]);
                }
            }
        }

        v2f pmA[5], pmB[5], mA[5], mB[5];
        #pragma unroll
        for (int c = 0; c < 5; ++c) {
            v2f aA0 = __builtin_elementwise_max(accA[c], zero2);
            v2f aA1 = __builtin_elementwise_max(accA[c + 1], zero2);
            pmA[c] = __builtin_elementwise_max(aA0, aA1);
            v2f aB0 = __builtin_elementwise_max(accB[c], zero2);
            v2f aB1 = __builtin_elementwise_max(accB[c + 1], zero2);
            pmB[c] = __builtin_elementwise_max(aB0, aB1);
        }
        #pragma unroll
        for (int c = 0; c < 5; ++c) {
            mA[c] = __builtin_elementwise_max(pmA[c], shfl2(pmA[c], lane + 1));
            mB[c] = __builtin_elementwise_max(pmB[c], shfl2(pmB[c], lane + 1));
        }
        if (r < 5) {
            const int oc0 = ocp * 2;
            #pragma unroll
            for (int c = 0; c < 5; ++c) {
                p2A[oc0 * 25 + r * 5 + c]       = mA[c].x;
                p2A[(oc0 + 1) * 25 + r * 5 + c] = mA[c].y;
                p2B[oc0 * 25 + r * 5 + c]       = mB[c].x;
                p2B[(oc0 + 1) * 25 + r * 5 + c] = mB[c].y;
            }
        }
    }
    __syncthreads();   // all 8 images' p2 ready; weight region becomes scratch

    // ---- fc1 (120x400) K-split x2: 240 threads, 8 images per thread ----
    float* scr = lds;   // [8][240] = 1920 floats over dead weight region
    if (tid < 240) {
        const int row  = tid >> 1;
        const int half = tid & 1;
        const float4* wrow = (const float4*)(fc1w + row * 400) + half * 50;
        v2f acc[8];
        #pragma unroll
        for (int im = 0; im < 8; ++im) acc[im] = zero2;
        #pragma unroll 2
        for (int k = 0; k < 50; ++k) {
            float4 w4 = wrow[k];
            const v2f wxy = mk2(w4.x, w4.y), wzw = mk2(w4.z, w4.w);
            #pragma unroll
            for (int im = 0; im < 8; ++im) {
                const float4* ap = (const float4*)(lds + IMG_BASE + im * IMG_STRIDE + P2_OFF) + half * 50;
                float4 a = ap[k];
                acc[im] = __builtin_elementwise_fma(mk2(a.x, a.y), wxy, acc[im]);
                acc[im] = __builtin_elementwise_fma(mk2(a.z, a.w), wzw, acc[im]);
            }
        }
        #pragma unroll
        for (int im = 0; im < 8; ++im)
            scr[im * 240 + row * 2 + half] = acc[im].x + acc[im].y;
    }
    __syncthreads();

    // ---- fc1 reduce + bias + relu -> f1 per image ----
    if (tid < 120) {
        const float b = fc1b[tid];
        #pragma unroll
        for (int im = 0; im < 8; ++im) {
            float v = scr[im * 240 + tid * 2] + scr[im * 240 + tid * 2 + 1] + b;
            lds[IMG_BASE + im * IMG_STRIDE + F1_OFF + tid] = fmaxf(v, 0.f);
        }
    }
    __syncthreads();

    // ---- fc2 (84x120) + relu, 8 images per thread ----
    if (tid < 84) {
        const int row = tid;
        const float4* wrow = (const float4*)(fc2w + row * 120);
        const float bz = fc2b[row];
        v2f acc[8];
        #pragma unroll
        for (int im = 0; im < 8; ++im) acc[im] = zero2;
        #pragma unroll 2
        for (int k = 0; k < 30; ++k) {
            float4 w4 = wrow[k];
            const v2f wxy = mk2(w4.x, w4.y), wzw = mk2(w4.z, w4.w);
            #pragma unroll
            for (int im = 0; im < 8; ++im) {
                const float4* fp = (const float4*)(lds + IMG_BASE + im * IMG_STRIDE + F1_OFF);
                float4 a = fp[k];
                acc[im] = __builtin_elementwise_fma(mk2(a.x, a.y), wxy, acc[im]);
                acc[im] = __builtin_elementwise_fma(mk2(a.z, a.w), wzw, acc[im]);
            }
        }
        #pragma unroll
        for (int im = 0; im < 8; ++im)
            lds[IMG_BASE + im * IMG_STRIDE + F2_OFF + row] =
                fmaxf(acc[im].x + acc[im].y + bz, 0.f);
    }
    __syncthreads();

    // ---- fc3 (10x84) -> out, 8 images x 10 rows = 80 threads ----
    if (tid < 80) {
        const int im  = tid / 10;
        const int row = tid - im * 10;
        const float4* wrow = (const float4*)(fc3w + row * 84);
        const float4* f2 = (const float4*)(lds + IMG_BASE + im * IMG_STRIDE + F2_OFF);
        v2f acc = zero2;
        #pragma unroll
        for (int k = 0; k < 21; ++k) {
            float4 w4 = wrow[k];
            float4 a = f2[k];
            acc = __builtin_elementwise_fma(mk2(a.x, a.y), mk2(w4.x, w4.y), acc);
            acc = __builtin_elementwise_fma(mk2(a.z, a.w), mk2(w4.z, w4.w), acc);
        }
        out[(size_t)(img0 + im) * 10 + row] = acc.x + acc.y + fc3b[row];
    }
}

extern "C" void kernel_launch(void* const* d_in, const int* in_sizes, int n_in,
                              void* d_out, int out_size, void* d_ws, size_t ws_size,
                              hipStream_t stream) {
    const float* x    = (const float*)d_in[0];
    const float* w1   = (const float*)d_in[1];
    const float* w2   = (const float*)d_in[2];
    const float* fc1w = (const float*)d_in[3];
    const float* fc1b = (const float*)d_in[4];
    const float* fc2w = (const float*)d_in[5];
    const float* fc2b = (const float*)d_in[6];
    const float* fc3w = (const float*)d_in[7];
    const float* fc3b = (const float*)d_in[8];
    float* out = (float*)d_out;

    const int B = in_sizes[0] / 3072;       // 8192
    const int grid = B / IPB;               // 1024
    lenet_fused<<<grid, THREADS, 0, stream>>>(x, w1, w2, fc1w, fc1b,
                                              fc2w, fc2b, fc3w, fc3b, out);
}